// Round 1
// baseline (7670.459 us; speedup 1.0000x reference)
//
#include <hip/hip_runtime.h>

typedef unsigned short u16;
typedef unsigned int u32;
typedef __bf16 bf16x8 __attribute__((ext_vector_type(8)));
typedef float f32x4 __attribute__((ext_vector_type(4)));

#define SEQ 4096
#define HM 1536
#define QKVN 4608
#define REG_PER_H (624*4096)   // score elems per head (624 key-block slots)

__device__ inline u16 f2b(float f){
  u32 u = __builtin_bit_cast(u32, f);
  return (u16)((u + 0x7fffu + ((u>>16)&1u)) >> 16);   // RNE, finite inputs
}
__device__ inline bf16x8 ld8(const u16* p){ return *reinterpret_cast<const bf16x8*>(p); }
__device__ inline int cum_of(int qb){ return qb==0?0:(qb==63?560:64+(qb-1)*8); }

// ---------------- convert fp32 -> bf16 (flat, x input) ----------------
__global__ void cvt_k(const float* __restrict__ in, u16* __restrict__ outp, int n4){
  int i = blockIdx.x*256 + threadIdx.x;
  if (i < n4){
    float4 f = reinterpret_cast<const float4*>(in)[i];
    ushort4 u; u.x=f2b(f.x); u.y=f2b(f.y); u.z=f2b(f.z); u.w=f2b(f.w);
    reinterpret_cast<ushort4*>(outp)[i] = u;
  }
}

// ---------------- transpose+convert W[K][N] f32 -> Wt[N][K] bf16 ----------------
__global__ void tconv(const float* __restrict__ W, u16* __restrict__ Wt, int K, int N){
  __shared__ float tile[32][33];
  int n0 = blockIdx.x*32, k0 = blockIdx.y*32;
  int tx = threadIdx.x, ty = threadIdx.y;            // (32,8)
  #pragma unroll
  for (int i=0;i<4;i++){
    int kk = ty + i*8;
    tile[kk][tx] = W[(size_t)(k0+kk)*N + n0 + tx];
  }
  __syncthreads();
  #pragma unroll
  for (int i=0;i<4;i++){
    int nn = ty + i*8;
    Wt[(size_t)(n0+nn)*K + k0 + tx] = f2b(tile[tx][nn]);
  }
}

// ---------------- bf16 transpose: qkv v-cols [S][1536] -> vt[1536][S] ----------------
__global__ void vtrans_k(const u16* __restrict__ qkv, u16* __restrict__ vt){
  __shared__ u16 tile[32][33];
  int c0 = blockIdx.x*32, s0 = blockIdx.y*32;
  int tx = threadIdx.x, ty = threadIdx.y;            // (32,8)
  #pragma unroll
  for (int i=0;i<4;i++)
    tile[ty+i*8][tx] = qkv[(size_t)(s0+ty+i*8)*QKVN + 3072 + c0 + tx];
  __syncthreads();
  #pragma unroll
  for (int i=0;i<4;i++)
    vt[(size_t)(c0+ty+i*8)*SEQ + s0 + tx] = tile[tx][ty+i*8];
}

__global__ void concat3_k(float* __restrict__ dst, const float* __restrict__ a,
                          const float* __restrict__ b, const float* __restrict__ c){
  int i = blockIdx.x*256 + threadIdx.x;
  if (i < 1536){ dst[i]=a[i]; dst[1536+i]=b[i]; dst[3072+i]=c[i]; }
}

// ---------------- GEMM: A[M][K] bf16 @ Bt[N][K] bf16 -> epilogue ----------------
// MODE: 0 plain bf16  1 +resid f32  2 gelu bf16  3 relu bf16  4 plain f32  5 embed f32
template<int MODE>
__global__ void gemm_k(const u16* __restrict__ A, const u16* __restrict__ Bt,
                       const float* __restrict__ bias, const float* __restrict__ resid,
                       const float* __restrict__ pos, const float* __restrict__ tok,
                       u16* __restrict__ outB, float* __restrict__ outF,
                       int M, int N, int K){
  __shared__ __align__(16) u16 As[128][40];
  __shared__ __align__(16) u16 Bs[128][40];
  const int t = threadIdx.x;
  const int m0 = blockIdx.y*128, n0 = blockIdx.x*128;
  const int w = t>>6, l = t&63;
  const int wm = (w>>1)*64, wn = (w&1)*64;
  const int lr = l&15, lg = l>>4;
  f32x4 acc[4][4] = {};

  for (int k0 = 0; k0 < K; k0 += 32){
    #pragma unroll
    for (int i=0;i<2;i++){
      int c = t + i*256;
      int r = c>>2, k8 = (c&3)*8;
      *reinterpret_cast<int4*>(&As[r][k8]) =
          *reinterpret_cast<const int4*>(&A[(size_t)(m0+r)*K + k0 + k8]);
      *reinterpret_cast<int4*>(&Bs[r][k8]) =
          *reinterpret_cast<const int4*>(&Bt[(size_t)(n0+r)*K + k0 + k8]);
    }
    __syncthreads();
    bf16x8 af[4], bfr[4];
    #pragma unroll
    for (int i=0;i<4;i++){
      af[i]  = ld8(&As[wm + i*16 + lr][lg*8]);
      bfr[i] = ld8(&Bs[wn + i*16 + lr][lg*8]);
    }
    #pragma unroll
    for (int i=0;i<4;i++)
      #pragma unroll
      for (int j=0;j<4;j++)
        acc[i][j] = __builtin_amdgcn_mfma_f32_16x16x32_bf16(af[i], bfr[j], acc[i][j], 0,0,0);
    __syncthreads();
  }

  #pragma unroll
  for (int i=0;i<4;i++){
    #pragma unroll
    for (int j=0;j<4;j++){
      int col = n0 + wn + j*16 + lr;
      float bv = bias[col];
      #pragma unroll
      for (int r2=0;r2<4;r2++){
        int row = m0 + wm + i*16 + lg*4 + r2;
        float v = acc[i][j][r2] + bv;
        size_t idx = (size_t)row*N + col;
        if (MODE==0) outB[idx] = f2b(v);
        else if (MODE==1) outF[idx] = v + resid[idx];
        else if (MODE==2){
          float g = 0.5f*v*(1.f + tanhf(0.7978845608028654f*(v + 0.044715f*v*v*v)));
          outB[idx] = f2b(g);
        }
        else if (MODE==3) outB[idx] = f2b(fmaxf(v, 0.f));
        else if (MODE==4) outF[idx] = v;
        else if (MODE==5) outF[idx] = v + pos[idx] + tok[col];
      }
    }
  }
}

// ---------------- LayerNorm: row of 1536, block per row ----------------
__global__ void ln_k(const float* __restrict__ in, const float* __restrict__ g,
                     const float* __restrict__ bta, float* __restrict__ xf,
                     u16* __restrict__ xb){
  const int row = blockIdx.x, t = threadIdx.x;
  const float* rp = in + (size_t)row*HM;
  float v[6]; float s=0.f, s2=0.f;
  #pragma unroll
  for (int i=0;i<6;i++){ v[i] = rp[t + i*256]; s += v[i]; s2 += v[i]*v[i]; }
  #pragma unroll
  for (int o=32;o;o>>=1){ s += __shfl_down(s,o,64); s2 += __shfl_down(s2,o,64); }
  __shared__ float red[8];
  if ((t&63)==0){ red[t>>6]=s; red[4+(t>>6)]=s2; }
  __syncthreads();
  s = red[0]+red[1]+red[2]+red[3]; s2 = red[4]+red[5]+red[6]+red[7];
  float mean = s*(1.f/1536.f);
  float var  = s2*(1.f/1536.f) - mean*mean;
  float inv  = rsqrtf(var + 1e-12f);
  #pragma unroll
  for (int i=0;i<6;i++){
    int c = t + i*256;
    float y = (v[i]-mean)*inv*g[c] + bta[c];
    xf[(size_t)row*HM + c] = y;
    xb[(size_t)row*HM + c] = f2b(y);
  }
}

// ---------------- attention scores: wave per (head, key-block slot) ----------------
__global__ void scores_k(const u16* __restrict__ qkv, const int* __restrict__ kblocks,
                         const int* __restrict__ amask, float* __restrict__ sc){
  const int t = threadIdx.x, w = t>>6, l = t&63;
  const int sw = blockIdx.x*4 + w;        // 0..4991
  const int h = sw/624, slot = sw%624;
  int qb, j, len;
  if (slot < 64){ qb=0; j=slot; len=64; }
  else if (slot < 560){ qb = 1 + (slot-64)/8; j = (slot-64)&7; len=8; }
  else { qb=63; j=slot-560; len=64; }
  const int kb = (len==64) ? j : kblocks[(qb-1)*8 + j];
  const int lr = l&15, lg = l>>4;
  const u16* qp = qkv + (size_t)(qb*64)*QKVN + h*192;
  const u16* kp = qkv + (size_t)(kb*64)*QKVN + 1536 + h*192;
  f32x4 acc[4][4] = {};
  for (int d0=0; d0<192; d0+=32){
    bf16x8 aq[4], bk_[4];
    #pragma unroll
    for (int i=0;i<4;i++){
      aq[i]  = ld8(qp + (size_t)(i*16+lr)*QKVN + d0 + lg*8);
      bk_[i] = ld8(kp + (size_t)(i*16+lr)*QKVN + d0 + lg*8);
    }
    #pragma unroll
    for (int i=0;i<4;i++)
      #pragma unroll
      for (int jn=0;jn<4;jn++)
        acc[i][jn] = __builtin_amdgcn_mfma_f32_16x16x32_bf16(aq[i], bk_[jn], acc[i][jn], 0,0,0);
  }
  float* base = sc + (size_t)h*REG_PER_H + (size_t)cum_of(qb)*4096;
  const int ls = len*64;
  const float scale = 0.07216878364870323f;   // 1/sqrt(192)
  #pragma unroll
  for (int i=0;i<4;i++)
    #pragma unroll
    for (int jn=0;jn<4;jn++)
      #pragma unroll
      for (int r2=0;r2<4;r2++){
        int row = i*16 + lg*4 + r2;
        int c   = jn*16 + lr;
        float m = (float)amask[kb*64 + c];
        base[(size_t)row*ls + j*64 + c] = acc[i][jn][r2]*scale - 1e9f*(1.f - m);
      }
}

// ---------------- row softmax (wave per row), writes normalized bf16 P ----------------
template<int LS>
__global__ void smax_k(const float* __restrict__ sc, u16* __restrict__ pb){
  const int t = threadIdx.x, w = t>>6, l = t&63;
  const int rid = blockIdx.x*4 + w;
  int h, qb, row;
  if (LS == 512){ h = rid/(62*64); int rem = rid%(62*64); qb = 1 + rem/64; row = rem&63; }
  else          { h = rid/128;     int rem = rid%128;     qb = (rem>>6)?63:0; row = rem&63; }
  size_t base_off = (size_t)h*REG_PER_H + (size_t)cum_of(qb)*4096 + (size_t)row*LS;
  const float* base = sc + base_off;
  u16* pbase = pb + base_off;
  constexpr int NE = LS/64;
  float v[NE]; float mx = -3e38f;
  #pragma unroll
  for (int i=0;i<NE;i++){ v[i] = base[i*64 + l]; mx = fmaxf(mx, v[i]); }
  #pragma unroll
  for (int o=32;o;o>>=1) mx = fmaxf(mx, __shfl_xor(mx, o, 64));
  float s = 0.f;
  #pragma unroll
  for (int i=0;i<NE;i++){ v[i] = __expf(v[i]-mx); s += v[i]; }
  #pragma unroll
  for (int o=32;o;o>>=1) s += __shfl_xor(s, o, 64);
  float inv = 1.f/s;
  #pragma unroll
  for (int i=0;i<NE;i++) pbase[i*64 + l] = f2b(v[i]*inv);
}

// ---------------- PV: block per (head, qblock); wave owns 48 of 192 dims ----------------
__global__ void pv_k(const u16* __restrict__ pb, const u16* __restrict__ vt,
                     const int* __restrict__ kblocks, u16* __restrict__ ctx){
  const int t = threadIdx.x, w = t>>6, l = t&63;
  const int b = blockIdx.x;
  const int qb = b&63, h = b>>6;
  const int lr = l&15, lg = l>>4;
  const int len = (qb==0 || qb==63) ? 64 : 8;
  const u16* pbase = pb + (size_t)h*REG_PER_H + (size_t)cum_of(qb)*4096;
  const int ls = len*64;
  f32x4 acc[4][3] = {};
  const int nst = len*2;
  for (int ks=0; ks<nst; ks++){
    int jj = ks>>1;
    int kb = (len==64) ? jj : kblocks[(qb-1)*8 + jj];
    int kk0 = ks*32;
    int sbase = kb*64 + (ks&1)*32 + lg*8;
    bf16x8 ap[4], bv_[3];
    #pragma unroll
    for (int i=0;i<4;i++) ap[i] = ld8(pbase + (size_t)(i*16+lr)*ls + kk0 + lg*8);
    #pragma unroll
    for (int jn=0;jn<3;jn++) bv_[jn] = ld8(vt + (size_t)(h*192 + w*48 + jn*16 + lr)*SEQ + sbase);
    #pragma unroll
    for (int i=0;i<4;i++)
      #pragma unroll
      for (int jn=0;jn<3;jn++)
        acc[i][jn] = __builtin_amdgcn_mfma_f32_16x16x32_bf16(ap[i], bv_[jn], acc[i][jn], 0,0,0);
  }
  #pragma unroll
  for (int i=0;i<4;i++)
    #pragma unroll
    for (int jn=0;jn<3;jn++)
      #pragma unroll
      for (int r2=0;r2<4;r2++){
        int row = qb*64 + i*16 + lg*4 + r2;
        int col = h*192 + w*48 + jn*16 + lr;
        ctx[(size_t)row*HM + col] = f2b(acc[i][jn][r2]);
      }
}

// =====================================================================
extern "C" void kernel_launch(void* const* d_in, const int* in_sizes, int n_in,
                              void* d_out, int out_size, void* d_ws, size_t ws_size,
                              hipStream_t stream){
  const float* x       = (const float*)d_in[0];
  const float* proj_w  = (const float*)d_in[1];
  const float* proj_b  = (const float*)d_in[2];
  const float* pos_emb = (const float*)d_in[3];
  const float* tok_emb = (const float*)d_in[4];
  const float* embs    = (const float*)d_in[5];
  const float* embb    = (const float*)d_in[6];
  const float* Wq  = (const float*)d_in[7];
  const float* bq  = (const float*)d_in[8];
  const float* Wk  = (const float*)d_in[9];
  const float* bk  = (const float*)d_in[10];
  const float* Wv  = (const float*)d_in[11];
  const float* bv  = (const float*)d_in[12];
  const float* Wo  = (const float*)d_in[13];
  const float* bo  = (const float*)d_in[14];
  const float* l1s = (const float*)d_in[15];
  const float* l1b = (const float*)d_in[16];
  const float* Wi  = (const float*)d_in[17];
  const float* bi  = (const float*)d_in[18];
  const float* Wo2 = (const float*)d_in[19];
  const float* bo2 = (const float*)d_in[20];
  const float* l2s = (const float*)d_in[21];
  const float* l2b = (const float*)d_in[22];
  const float* cw1 = (const float*)d_in[23];
  const float* cb1 = (const float*)d_in[24];
  const float* cw2 = (const float*)d_in[25];
  const float* cb2 = (const float*)d_in[26];
  const int* amask = (const int*)d_in[27];
  const int* kblk  = (const int*)d_in[28];
  float* out = (float*)d_out;

  char* base = (char*)d_ws;
  size_t off = 0;
  auto carve = [&](size_t bytes)->char*{
    char* p = base + off; off += (bytes + 255) & ~(size_t)255; return p;
  };
  float* xf32  = (float*)carve(4096ULL*1536*4);
  float* preln = (float*)carve(4096ULL*1536*4);
  u16*   xbf   = (u16*)  carve(4096ULL*1536*2);
  u16*   xinbf = (u16*)  carve(4096ULL*1280*2);
  u16*   qkv   = (u16*)  carve(4096ULL*4608*2);
  u16*   vt    = (u16*)  carve(1536ULL*4096*2);
  u16*   ctx   = (u16*)  carve(4096ULL*1536*2);
  u16*   ff1   = (u16*)  carve(4096ULL*3072*2);
  u16*   cls1  = (u16*)  carve(4096ULL*512*2);
  u16*   wt    = (u16*)  carve(4608ULL*1536*2);
  float* b3    = (float*)carve(4608ULL*4);
  float* sc    = (float*)carve(8ULL*REG_PER_H*4);
  u16*   pbuf  = (u16*)  carve(8ULL*REG_PER_H*2);
  if (off > ws_size) return;   // workspace too small: fail cleanly, no OOB writes

  const dim3 tb32(32,8);

  // ---- embedding ----
  cvt_k<<<5120, 256, 0, stream>>>(x, xinbf, 4096*1280/4);
  tconv<<<dim3(48,40), tb32, 0, stream>>>(proj_w, wt, 1280, 1536);
  gemm_k<5><<<dim3(12,32), 256, 0, stream>>>(xinbf, wt, proj_b, nullptr, pos_emb, tok_emb,
                                             nullptr, preln, 4096, 1536, 1280);
  ln_k<<<4096, 256, 0, stream>>>(preln, embs, embb, xf32, xbf);

  // ---- encoder layers ----
  for (int l = 0; l < 12; ++l){
    const float* wq  = Wq  + (size_t)l*1536*1536;
    const float* wk  = Wk  + (size_t)l*1536*1536;
    const float* wv  = Wv  + (size_t)l*1536*1536;
    const float* wo  = Wo  + (size_t)l*1536*1536;
    const float* wi  = Wi  + (size_t)l*1536*3072;
    const float* wo2 = Wo2 + (size_t)l*3072*1536;
    const float* bql = bq  + (size_t)l*1536;
    const float* bkl = bk  + (size_t)l*1536;
    const float* bvl = bv  + (size_t)l*1536;
    const float* bol = bo  + (size_t)l*1536;
    const float* bil = bi  + (size_t)l*3072;
    const float* bo2l= bo2 + (size_t)l*1536;
    const float* g1  = l1s + (size_t)l*1536;
    const float* be1 = l1b + (size_t)l*1536;
    const float* g2  = l2s + (size_t)l*1536;
    const float* be2 = l2b + (size_t)l*1536;

    // fused QKV
    tconv<<<dim3(48,48), tb32, 0, stream>>>(wq, wt,                    1536, 1536);
    tconv<<<dim3(48,48), tb32, 0, stream>>>(wk, wt + 1536ULL*1536,     1536, 1536);
    tconv<<<dim3(48,48), tb32, 0, stream>>>(wv, wt + 2ULL*1536*1536,   1536, 1536);
    concat3_k<<<6, 256, 0, stream>>>(b3, bql, bkl, bvl);
    gemm_k<0><<<dim3(36,32), 256, 0, stream>>>(xbf, wt, b3, nullptr, nullptr, nullptr,
                                               qkv, nullptr, 4096, 4608, 1536);
    vtrans_k<<<dim3(48,128), tb32, 0, stream>>>(qkv, vt);

    // block-sparse attention
    scores_k<<<1248, 256, 0, stream>>>(qkv, kblk, amask, sc);
    smax_k<512> <<<7936, 256, 0, stream>>>(sc, pbuf);
    smax_k<4096><<<256,  256, 0, stream>>>(sc, pbuf);
    pv_k<<<512, 256, 0, stream>>>(pbuf, vt, kblk, ctx);

    // attention output projection + residual + LN
    tconv<<<dim3(48,48), tb32, 0, stream>>>(wo, wt, 1536, 1536);
    gemm_k<1><<<dim3(12,32), 256, 0, stream>>>(ctx, wt, bol, xf32, nullptr, nullptr,
                                               nullptr, preln, 4096, 1536, 1536);
    ln_k<<<4096, 256, 0, stream>>>(preln, g1, be1, xf32, xbf);

    // FFN
    tconv<<<dim3(96,48), tb32, 0, stream>>>(wi, wt, 1536, 3072);
    gemm_k<2><<<dim3(24,32), 256, 0, stream>>>(xbf, wt, bil, nullptr, nullptr, nullptr,
                                               ff1, nullptr, 4096, 3072, 1536);
    tconv<<<dim3(48,96), tb32, 0, stream>>>(wo2, wt, 3072, 1536);
    gemm_k<1><<<dim3(12,32), 256, 0, stream>>>(ff1, wt, bo2l, xf32, nullptr, nullptr,
                                               nullptr, preln, 4096, 1536, 3072);
    ln_k<<<4096, 256, 0, stream>>>(preln, g2, be2, xf32, xbf);
  }

  // ---- classifier head ----
  tconv<<<dim3(16,48), tb32, 0, stream>>>(cw1, wt, 1536, 512);
  gemm_k<3><<<dim3(4,32), 256, 0, stream>>>(xbf, wt, cb1, nullptr, nullptr, nullptr,
                                            cls1, nullptr, 4096, 512, 1536);
  tconv<<<dim3(8,16), tb32, 0, stream>>>(cw2, wt, 512, 256);
  gemm_k<4><<<dim3(2,32), 256, 0, stream>>>(cls1, wt, cb2, nullptr, nullptr, nullptr,
                                            nullptr, out, 4096, 256, 512);

  (void)in_sizes; (void)n_in; (void)out_size;
}

// Round 2
// 7361.900 us; speedup vs baseline: 1.0419x; 1.0419x over previous
//
#include <hip/hip_runtime.h>

typedef unsigned short u16;
typedef unsigned int u32;
typedef __bf16 bf16x8 __attribute__((ext_vector_type(8)));
typedef float f32x4 __attribute__((ext_vector_type(4)));

#define SEQ 4096
#define HM 1536
#define QKVN 4608

__device__ inline u16 f2b(float f){
  u32 u = __builtin_bit_cast(u32, f);
  return (u16)((u + 0x7fffu + ((u>>16)&1u)) >> 16);   // RNE, finite inputs
}
__device__ inline bf16x8 ld8(const u16* p){ return *reinterpret_cast<const bf16x8*>(p); }
__device__ inline void gload16(const void* g, void* l){
  __builtin_amdgcn_global_load_lds((const __attribute__((address_space(1))) void*)g,
                                   (__attribute__((address_space(3))) void*)l, 16, 0, 0);
}

// ---------------- convert fp32 -> bf16 (flat) ----------------
__global__ void cvt_k(const float* __restrict__ in, u16* __restrict__ outp, int n4){
  int i = blockIdx.x*256 + threadIdx.x;
  if (i < n4){
    float4 f = reinterpret_cast<const float4*>(in)[i];
    ushort4 u; u.x=f2b(f.x); u.y=f2b(f.y); u.z=f2b(f.z); u.w=f2b(f.w);
    reinterpret_cast<ushort4*>(outp)[i] = u;
  }
}

// ---------------- transpose+convert W[K][N] f32 -> Wt[N][K] bf16 ----------------
__global__ void tconv(const float* __restrict__ W, u16* __restrict__ Wt, int K, int N){
  __shared__ float tile[32][33];
  int n0 = blockIdx.x*32, k0 = blockIdx.y*32;
  int tx = threadIdx.x, ty = threadIdx.y;            // (32,8)
  #pragma unroll
  for (int i=0;i<4;i++){
    int kk = ty + i*8;
    tile[kk][tx] = W[(size_t)(k0+kk)*N + n0 + tx];
  }
  __syncthreads();
  #pragma unroll
  for (int i=0;i<4;i++){
    int nn = ty + i*8;
    Wt[(size_t)(n0+nn)*K + k0 + tx] = f2b(tile[tx][nn]);
  }
}

// ---------------- bf16 transpose: qkv v-cols [S][1536] -> vt[1536][S] ----------------
__global__ void vtrans_k(const u16* __restrict__ qkv, u16* __restrict__ vt){
  __shared__ u16 tile[32][33];
  int c0 = blockIdx.x*32, s0 = blockIdx.y*32;
  int tx = threadIdx.x, ty = threadIdx.y;            // (32,8)
  #pragma unroll
  for (int i=0;i<4;i++)
    tile[ty+i*8][tx] = qkv[(size_t)(s0+ty+i*8)*QKVN + 3072 + c0 + tx];
  __syncthreads();
  #pragma unroll
  for (int i=0;i<4;i++)
    vt[(size_t)(c0+ty+i*8)*SEQ + s0 + tx] = tile[tx][ty+i*8];
}

__global__ void concat3_k(float* __restrict__ dst, const float* __restrict__ a,
                          const float* __restrict__ b, const float* __restrict__ c){
  int i = blockIdx.x*256 + threadIdx.x;
  if (i < 1536){ dst[i]=a[i]; dst[1536+i]=b[i]; dst[3072+i]=c[i]; }
}

// ---------------- GEMM (m97 structure): A[M][K] @ Bt[N][K] bf16, global_load_lds ----
// MODE: 0 plain bf16  1 +resid f32  2 gelu bf16  3 relu bf16  4 plain f32  5 embed f32
template<int MODE>
__global__ __launch_bounds__(256) void gemm_k(
                       const u16* __restrict__ A, const u16* __restrict__ Bt,
                       const float* __restrict__ bias, const float* __restrict__ resid,
                       const float* __restrict__ pos, const float* __restrict__ tok,
                       u16* __restrict__ outB, float* __restrict__ outF,
                       int M, int N, int K){
  __shared__ __align__(16) u16 As[128*32];
  __shared__ __align__(16) u16 Bs[128*32];
  const int t = threadIdx.x;
  const int m0 = blockIdx.y*128, n0 = blockIdx.x*128;
  const int w = t>>6, l = t&63;
  const int wm = (w>>1)*64, wn = (w&1)*64;
  const int lr = l&15, lg = l>>4;
  // staging: issue i in {0,1}: rows w*32+i*16+(l>>2), cols (l&3)*8; LDS linear
  const int srow = w*32 + (l>>2);
  const int scol = (l&3)*8;
  const u16* Ap = A  + (size_t)(m0 + srow)*K + scol;
  const u16* Bp = Bt + (size_t)(n0 + srow)*K + scol;
  f32x4 acc[4][4] = {};

  for (int k0 = 0; k0 < K; k0 += 32){
    #pragma unroll
    for (int i=0;i<2;i++){
      gload16(Ap + (size_t)i*16*K + k0, &As[(w*2+i)*512]);
      gload16(Bp + (size_t)i*16*K + k0, &Bs[(w*2+i)*512]);
    }
    __syncthreads();
    bf16x8 af[4], bfr[4];
    #pragma unroll
    for (int i=0;i<4;i++){
      af[i]  = ld8(&As[(wm + i*16 + lr)*32 + lg*8]);
      bfr[i] = ld8(&Bs[(wn + i*16 + lr)*32 + lg*8]);
    }
    #pragma unroll
    for (int i=0;i<4;i++)
      #pragma unroll
      for (int j=0;j<4;j++)
        acc[i][j] = __builtin_amdgcn_mfma_f32_16x16x32_bf16(af[i], bfr[j], acc[i][j], 0,0,0);
    __syncthreads();
  }

  #pragma unroll
  for (int i=0;i<4;i++){
    #pragma unroll
    for (int j=0;j<4;j++){
      int col = n0 + wn + j*16 + lr;
      float bv = bias[col];
      #pragma unroll
      for (int r2=0;r2<4;r2++){
        int row = m0 + wm + i*16 + lg*4 + r2;
        float v = acc[i][j][r2] + bv;
        size_t idx = (size_t)row*N + col;
        if (MODE==0) outB[idx] = f2b(v);
        else if (MODE==1) outF[idx] = v + resid[idx];
        else if (MODE==2){
          float g = 0.5f*v*(1.f + tanhf(0.7978845608028654f*(v + 0.044715f*v*v*v)));
          outB[idx] = f2b(g);
        }
        else if (MODE==3) outB[idx] = f2b(fmaxf(v, 0.f));
        else if (MODE==4) outF[idx] = v;
        else if (MODE==5) outF[idx] = v + pos[idx] + tok[col];
      }
    }
  }
}

// ---------------- LayerNorm: row of 1536, block per row ----------------
__global__ void ln_k(const float* __restrict__ in, const float* __restrict__ g,
                     const float* __restrict__ bta, float* __restrict__ xf,
                     u16* __restrict__ xb){
  const int row = blockIdx.x, t = threadIdx.x;
  const float* rp = in + (size_t)row*HM;
  float v[6]; float s=0.f, s2=0.f;
  #pragma unroll
  for (int i=0;i<6;i++){ v[i] = rp[t + i*256]; s += v[i]; s2 += v[i]*v[i]; }
  #pragma unroll
  for (int o=32;o;o>>=1){ s += __shfl_down(s,o,64); s2 += __shfl_down(s2,o,64); }
  __shared__ float red[8];
  if ((t&63)==0){ red[t>>6]=s; red[4+(t>>6)]=s2; }
  __syncthreads();
  s = red[0]+red[1]+red[2]+red[3]; s2 = red[4]+red[5]+red[6]+red[7];
  float mean = s*(1.f/1536.f);
  float var  = s2*(1.f/1536.f) - mean*mean;
  float inv  = rsqrtf(var + 1e-12f);
  #pragma unroll
  for (int i=0;i<6;i++){
    int c = t + i*256;
    float y = (v[i]-mean)*inv*g[c] + bta[c];
    xf[(size_t)row*HM + c] = y;
    xb[(size_t)row*HM + c] = f2b(y);
  }
}

// ---------------- fused block-sparse flash attention ----------------
// block = (h, qb); 4 waves; chunks of 256 keys (4 key-blocks, 1 per wave);
// online softmax across chunks; wave owns 48 of the 192 output dims.
__global__ __launch_bounds__(256, 2) void attn_k(
    const u16* __restrict__ qkv, const u16* __restrict__ vt,
    const int* __restrict__ kblocks, const int* __restrict__ amask,
    u16* __restrict__ ctx){
  __shared__ __align__(16) u16 sQ[64][200];
  __shared__ __align__(16) u16 sP[64][264];
  __shared__ float swm[4][64];
  __shared__ float swl[4][64];
  __shared__ float s_m[64];
  __shared__ float s_l[64];
  __shared__ float s_al[64];

  const int t = threadIdx.x, w = t>>6, l = t&63;
  const int lr = l&15, lg = l>>4;
  const int b = blockIdx.x;
  const int qb = b & 63, h = b >> 6;
  const bool edge = (qb==0) || (qb==63);
  const int NCH = edge ? 16 : 2;

  {
    const u16* qg = qkv + (size_t)(qb*64)*QKVN + h*192;
    #pragma unroll
    for (int i=0;i<6;i++){
      int idx = t + i*256;            // 0..1535
      int row = idx/24, c8 = idx%24;
      *reinterpret_cast<int4*>(&sQ[row][c8*8]) =
        *reinterpret_cast<const int4*>(qg + (size_t)row*QKVN + c8*8);
    }
  }
  if (t < 64){ s_m[t] = -3.0e38f; s_l[t] = 0.f; }
  __syncthreads();

  f32x4 accO[4][3] = {};
  const float scale = 0.07216878364870323f;   // 1/sqrt(192)

  for (int c = 0; c < NCH; ++c){
    // ---- phase A: S = Q K^T for this wave's key-block (64 keys)
    const int jj = c*4 + w;
    const int kb = edge ? jj : kblocks[(qb-1)*8 + jj];
    const u16* kp = qkv + (size_t)(kb*64)*QKVN + 1536 + h*192;
    f32x4 acc[4][4] = {};
    #pragma unroll
    for (int d0=0; d0<192; d0+=32){
      bf16x8 aq[4], bk_[4];
      #pragma unroll
      for (int i=0;i<4;i++)  aq[i]  = ld8(&sQ[i*16+lr][d0+lg*8]);
      #pragma unroll
      for (int jn=0;jn<4;jn++) bk_[jn] = ld8(kp + (size_t)(jn*16+lr)*QKVN + d0 + lg*8);
      #pragma unroll
      for (int i=0;i<4;i++)
        #pragma unroll
        for (int jn=0;jn<4;jn++)
          acc[i][jn] = __builtin_amdgcn_mfma_f32_16x16x32_bf16(aq[i], bk_[jn], acc[i][jn], 0,0,0);
    }
    float mcol[4];
    #pragma unroll
    for (int jn=0;jn<4;jn++)
      mcol[jn] = -1e9f*(1.f - (float)amask[kb*64 + jn*16 + lr]);
    float rmax[4][4];
    #pragma unroll
    for (int i=0;i<4;i++)
      #pragma unroll
      for (int r2=0;r2<4;r2++){
        float mx = -3.0e38f;
        #pragma unroll
        for (int jn=0;jn<4;jn++){
          float sv = acc[i][jn][r2]*scale + mcol[jn];
          acc[i][jn][r2] = sv;
          mx = fmaxf(mx, sv);
        }
        #pragma unroll
        for (int o=1;o<16;o<<=1) mx = fmaxf(mx, __shfl_xor(mx, o, 64));
        rmax[i][r2] = mx;
      }
    if (lr == 0){
      #pragma unroll
      for (int i=0;i<4;i++)
        #pragma unroll
        for (int r2=0;r2<4;r2++)
          swm[w][i*16+lg*4+r2] = rmax[i][r2];
    }
    __syncthreads();                       // B1: swm visible; prev PV done
    if (t < 64){
      float mo = s_m[t];
      float mn = fmaxf(fmaxf(fmaxf(swm[0][t], swm[1][t]), fmaxf(swm[2][t], swm[3][t])), mo);
      s_al[t] = __expf(mo - mn);
      s_m[t]  = mn;
    }
    __syncthreads();                       // B2: s_m / s_al visible
    // ---- phase C: P = exp(S-m) -> sP bf16; partial row sums; rescale O
    #pragma unroll
    for (int i=0;i<4;i++)
      #pragma unroll
      for (int r2=0;r2<4;r2++){
        const int row = i*16 + lg*4 + r2;
        const float mrow = s_m[row];
        float ssum = 0.f;
        #pragma unroll
        for (int jn=0;jn<4;jn++){
          float p = __expf(acc[i][jn][r2] - mrow);
          ssum += p;
          sP[row][w*64 + jn*16 + lr] = f2b(p);
        }
        #pragma unroll
        for (int o=1;o<16;o<<=1) ssum += __shfl_xor(ssum, o, 64);
        if (lr == 0) swl[w][row] = ssum;
      }
    #pragma unroll
    for (int i=0;i<4;i++)
      #pragma unroll
      for (int r2=0;r2<4;r2++){
        float a = s_al[i*16+lg*4+r2];
        #pragma unroll
        for (int jn=0;jn<3;jn++) accO[i][jn][r2] *= a;
      }
    __syncthreads();                       // B3: sP / swl visible
    if (t < 64)
      s_l[t] = s_l[t]*s_al[t] + swl[0][t]+swl[1][t]+swl[2][t]+swl[3][t];
    // ---- phase E: O += P V (wave's 48 output dims, 256 chunk keys)
    int kb4[4];
    #pragma unroll
    for (int idx=0;idx<4;idx++)
      kb4[idx] = edge ? (c*4+idx) : kblocks[(qb-1)*8 + c*4 + idx];
    #pragma unroll
    for (int ks=0; ks<8; ks++){
      bf16x8 ap[4], bv_[3];
      #pragma unroll
      for (int i=0;i<4;i++) ap[i] = ld8(&sP[i*16+lr][ks*32 + lg*8]);
      const int sb = kb4[ks>>1]*64 + (ks&1)*32 + lg*8;
      #pragma unroll
      for (int jn=0;jn<3;jn++)
        bv_[jn] = ld8(vt + (size_t)(h*192 + w*48 + jn*16 + lr)*SEQ + sb);
      #pragma unroll
      for (int i=0;i<4;i++)
        #pragma unroll
        for (int jn=0;jn<3;jn++)
          accO[i][jn] = __builtin_amdgcn_mfma_f32_16x16x32_bf16(ap[i], bv_[jn], accO[i][jn], 0,0,0);
    }
  }
  __syncthreads();
  #pragma unroll
  for (int i=0;i<4;i++)
    #pragma unroll
    for (int r2=0;r2<4;r2++){
      const int row = i*16+lg*4+r2;
      const float inv = 1.f / s_l[row];
      #pragma unroll
      for (int jn=0;jn<3;jn++){
        const int col = h*192 + w*48 + jn*16 + lr;
        ctx[(size_t)(qb*64+row)*HM + col] = f2b(accO[i][jn][r2] * inv);
      }
    }
}

// =====================================================================
extern "C" void kernel_launch(void* const* d_in, const int* in_sizes, int n_in,
                              void* d_out, int out_size, void* d_ws, size_t ws_size,
                              hipStream_t stream){
  const float* x       = (const float*)d_in[0];
  const float* proj_w  = (const float*)d_in[1];
  const float* proj_b  = (const float*)d_in[2];
  const float* pos_emb = (const float*)d_in[3];
  const float* tok_emb = (const float*)d_in[4];
  const float* embs    = (const float*)d_in[5];
  const float* embb    = (const float*)d_in[6];
  const float* Wq  = (const float*)d_in[7];
  const float* bq  = (const float*)d_in[8];
  const float* Wk  = (const float*)d_in[9];
  const float* bk  = (const float*)d_in[10];
  const float* Wv  = (const float*)d_in[11];
  const float* bv  = (const float*)d_in[12];
  const float* Wo  = (const float*)d_in[13];
  const float* bo  = (const float*)d_in[14];
  const float* l1s = (const float*)d_in[15];
  const float* l1b = (const float*)d_in[16];
  const float* Wi  = (const float*)d_in[17];
  const float* bi  = (const float*)d_in[18];
  const float* Wo2 = (const float*)d_in[19];
  const float* bo2 = (const float*)d_in[20];
  const float* l2s = (const float*)d_in[21];
  const float* l2b = (const float*)d_in[22];
  const float* cw1 = (const float*)d_in[23];
  const float* cb1 = (const float*)d_in[24];
  const float* cw2 = (const float*)d_in[25];
  const float* cb2 = (const float*)d_in[26];
  const int* amask = (const int*)d_in[27];
  const int* kblk  = (const int*)d_in[28];
  float* out = (float*)d_out;

  char* base = (char*)d_ws;
  size_t off = 0;
  auto carve = [&](size_t bytes)->char*{
    char* p = base + off; off += (bytes + 255) & ~(size_t)255; return p;
  };
  float* xf32  = (float*)carve(4096ULL*1536*4);
  float* preln = (float*)carve(4096ULL*1536*4);
  u16*   xbf   = (u16*)  carve(4096ULL*1536*2);
  u16*   xinbf = (u16*)  carve(4096ULL*1280*2);
  u16*   qkv   = (u16*)  carve(4096ULL*4608*2);
  u16*   vt    = (u16*)  carve(1536ULL*4096*2);
  u16*   ctx   = (u16*)  carve(4096ULL*1536*2);
  u16*   ff1   = (u16*)  carve(4096ULL*3072*2);
  u16*   cls1  = (u16*)  carve(4096ULL*512*2);
  u16*   wt    = (u16*)  carve(4608ULL*1536*2);
  float* b3    = (float*)carve(4608ULL*4);
  if (off > ws_size) return;   // workspace too small: fail cleanly

  const dim3 tb32(32,8);

  // ---- embedding ----
  cvt_k<<<5120, 256, 0, stream>>>(x, xinbf, 4096*1280/4);
  tconv<<<dim3(48,40), tb32, 0, stream>>>(proj_w, wt, 1280, 1536);
  gemm_k<5><<<dim3(12,32), 256, 0, stream>>>(xinbf, wt, proj_b, nullptr, pos_emb, tok_emb,
                                             nullptr, preln, 4096, 1536, 1280);
  ln_k<<<4096, 256, 0, stream>>>(preln, embs, embb, xf32, xbf);

  // ---- encoder layers ----
  for (int l = 0; l < 12; ++l){
    const float* wq  = Wq  + (size_t)l*1536*1536;
    const float* wk  = Wk  + (size_t)l*1536*1536;
    const float* wv  = Wv  + (size_t)l*1536*1536;
    const float* wo  = Wo  + (size_t)l*1536*1536;
    const float* wi  = Wi  + (size_t)l*1536*3072;
    const float* wo2 = Wo2 + (size_t)l*3072*1536;
    const float* bql = bq  + (size_t)l*1536;
    const float* bkl = bk  + (size_t)l*1536;
    const float* bvl = bv  + (size_t)l*1536;
    const float* bol = bo  + (size_t)l*1536;
    const float* bil = bi  + (size_t)l*3072;
    const float* bo2l= bo2 + (size_t)l*1536;
    const float* g1  = l1s + (size_t)l*1536;
    const float* be1 = l1b + (size_t)l*1536;
    const float* g2  = l2s + (size_t)l*1536;
    const float* be2 = l2b + (size_t)l*1536;

    // fused QKV
    tconv<<<dim3(48,48), tb32, 0, stream>>>(wq, wt,                  1536, 1536);
    tconv<<<dim3(48,48), tb32, 0, stream>>>(wk, wt + 1536ULL*1536,   1536, 1536);
    tconv<<<dim3(48,48), tb32, 0, stream>>>(wv, wt + 2ULL*1536*1536, 1536, 1536);
    concat3_k<<<6, 256, 0, stream>>>(b3, bql, bkl, bvl);
    gemm_k<0><<<dim3(36,32), 256, 0, stream>>>(xbf, wt, b3, nullptr, nullptr, nullptr,
                                               qkv, nullptr, 4096, 4608, 1536);
    vtrans_k<<<dim3(48,128), tb32, 0, stream>>>(qkv, vt);

    // fused block-sparse attention
    attn_k<<<512, 256, 0, stream>>>(qkv, vt, kblk, amask, ctx);

    // attention output projection + residual + LN
    tconv<<<dim3(48,48), tb32, 0, stream>>>(wo, wt, 1536, 1536);
    gemm_k<1><<<dim3(12,32), 256, 0, stream>>>(ctx, wt, bol, xf32, nullptr, nullptr,
                                               nullptr, preln, 4096, 1536, 1536);
    ln_k<<<4096, 256, 0, stream>>>(preln, g1, be1, xf32, xbf);

    // FFN
    tconv<<<dim3(96,48), tb32, 0, stream>>>(wi, wt, 1536, 3072);
    gemm_k<2><<<dim3(24,32), 256, 0, stream>>>(xbf, wt, bil, nullptr, nullptr, nullptr,
                                               ff1, nullptr, 4096, 3072, 1536);
    tconv<<<dim3(48,96), tb32, 0, stream>>>(wo2, wt, 3072, 1536);
    gemm_k<1><<<dim3(12,32), 256, 0, stream>>>(ff1, wt, bo2l, xf32, nullptr, nullptr,
                                               nullptr, preln, 4096, 1536, 3072);
    ln_k<<<4096, 256, 0, stream>>>(preln, g2, be2, xf32, xbf);
  }

  // ---- classifier head ----
  tconv<<<dim3(16,48), tb32, 0, stream>>>(cw1, wt, 1536, 512);
  gemm_k<3><<<dim3(4,32), 256, 0, stream>>>(xbf, wt, cb1, nullptr, nullptr, nullptr,
                                            cls1, nullptr, 4096, 512, 1536);
  tconv<<<dim3(8,16), tb32, 0, stream>>>(cw2, wt, 512, 256);
  gemm_k<4><<<dim3(2,32), 256, 0, stream>>>(cls1, wt, cb2, nullptr, nullptr, nullptr,
                                            nullptr, out, 4096, 256, 512);

  (void)in_sizes; (void)n_in; (void)out_size;
}

// Round 3
// 5442.493 us; speedup vs baseline: 1.4094x; 1.3527x over previous
//
#include <hip/hip_runtime.h>

typedef unsigned short u16;
typedef unsigned int u32;
typedef __bf16 bf16x8 __attribute__((ext_vector_type(8)));
typedef float f32x4 __attribute__((ext_vector_type(4)));

#define SEQ 4096
#define HM 1536
#define QKVN 4608

__device__ inline u16 f2b(float f){
  u32 u = __builtin_bit_cast(u32, f);
  return (u16)((u + 0x7fffu + ((u>>16)&1u)) >> 16);   // RNE, finite inputs
}
__device__ inline bf16x8 ld8(const u16* p){ return *reinterpret_cast<const bf16x8*>(p); }
__device__ inline void gload16(const void* g, void* l){
  __builtin_amdgcn_global_load_lds((const __attribute__((address_space(1))) void*)g,
                                   (__attribute__((address_space(3))) void*)l, 16, 0, 0);
}

// ---------------- convert fp32 -> bf16 (flat) ----------------
__global__ void cvt_k(const float* __restrict__ in, u16* __restrict__ outp, int n4){
  int i = blockIdx.x*256 + threadIdx.x;
  if (i < n4){
    float4 f = reinterpret_cast<const float4*>(in)[i];
    ushort4 u; u.x=f2b(f.x); u.y=f2b(f.y); u.z=f2b(f.z); u.w=f2b(f.w);
    reinterpret_cast<ushort4*>(outp)[i] = u;
  }
}

// ---------------- transpose+convert W[K][N] f32 -> Wt[N][K] bf16 ----------------
__global__ void tconv(const float* __restrict__ W, u16* __restrict__ Wt, int K, int N){
  __shared__ float tile[32][33];
  int n0 = blockIdx.x*32, k0 = blockIdx.y*32;
  int tx = threadIdx.x, ty = threadIdx.y;            // (32,8)
  #pragma unroll
  for (int i=0;i<4;i++){
    int kk = ty + i*8;
    tile[kk][tx] = W[(size_t)(k0+kk)*N + n0 + tx];
  }
  __syncthreads();
  #pragma unroll
  for (int i=0;i<4;i++){
    int nn = ty + i*8;
    Wt[(size_t)(n0+nn)*K + k0 + tx] = f2b(tile[tx][nn]);
  }
}

// ---------------- bf16 transpose: qkv v-cols [S][1536] -> vt[1536][S] ----------------
__global__ void vtrans_k(const u16* __restrict__ qkv, u16* __restrict__ vt){
  __shared__ u16 tile[32][33];
  int c0 = blockIdx.x*32, s0 = blockIdx.y*32;
  int tx = threadIdx.x, ty = threadIdx.y;            // (32,8)
  #pragma unroll
  for (int i=0;i<4;i++)
    tile[ty+i*8][tx] = qkv[(size_t)(s0+ty+i*8)*QKVN + 3072 + c0 + tx];
  __syncthreads();
  #pragma unroll
  for (int i=0;i<4;i++)
    vt[(size_t)(c0+ty+i*8)*SEQ + s0 + tx] = tile[tx][ty+i*8];
}

__global__ void concat3_k(float* __restrict__ dst, const float* __restrict__ a,
                          const float* __restrict__ b, const float* __restrict__ c){
  int i = blockIdx.x*256 + threadIdx.x;
  if (i < 1536){ dst[i]=a[i]; dst[1536+i]=b[i]; dst[3072+i]=c[i]; }
}

// ---------------- GEMM (m97 structure): A[M][K] @ Bt[N][K] bf16, global_load_lds ----
// MODE: 0 plain bf16  1 +resid f32  2 gelu bf16  3 relu bf16  4 plain f32  5 embed f32
template<int MODE>
__global__ __launch_bounds__(256) void gemm_k(
                       const u16* __restrict__ A, const u16* __restrict__ Bt,
                       const float* __restrict__ bias, const float* __restrict__ resid,
                       const float* __restrict__ pos, const float* __restrict__ tok,
                       u16* __restrict__ outB, float* __restrict__ outF,
                       int M, int N, int K){
  __shared__ __align__(16) u16 As[128*32];
  __shared__ __align__(16) u16 Bs[128*32];
  const int t = threadIdx.x;
  const int m0 = blockIdx.y*128, n0 = blockIdx.x*128;
  const int w = t>>6, l = t&63;
  const int wm = (w>>1)*64, wn = (w&1)*64;
  const int lr = l&15, lg = l>>4;
  const int srow = w*32 + (l>>2);
  const int scol = (l&3)*8;
  const u16* Ap = A  + (size_t)(m0 + srow)*K + scol;
  const u16* Bp = Bt + (size_t)(n0 + srow)*K + scol;
  f32x4 acc[4][4] = {};

  for (int k0 = 0; k0 < K; k0 += 32){
    #pragma unroll
    for (int i=0;i<2;i++){
      gload16(Ap + (size_t)i*16*K + k0, &As[(w*2+i)*512]);
      gload16(Bp + (size_t)i*16*K + k0, &Bs[(w*2+i)*512]);
    }
    __syncthreads();
    bf16x8 af[4], bfr[4];
    #pragma unroll
    for (int i=0;i<4;i++){
      af[i]  = ld8(&As[(wm + i*16 + lr)*32 + lg*8]);
      bfr[i] = ld8(&Bs[(wn + i*16 + lr)*32 + lg*8]);
    }
    #pragma unroll
    for (int i=0;i<4;i++)
      #pragma unroll
      for (int j=0;j<4;j++)
        acc[i][j] = __builtin_amdgcn_mfma_f32_16x16x32_bf16(af[i], bfr[j], acc[i][j], 0,0,0);
    __syncthreads();
  }

  #pragma unroll
  for (int i=0;i<4;i++){
    #pragma unroll
    for (int j=0;j<4;j++){
      int col = n0 + wn + j*16 + lr;
      float bv = bias[col];
      #pragma unroll
      for (int r2=0;r2<4;r2++){
        int row = m0 + wm + i*16 + lg*4 + r2;
        float v = acc[i][j][r2] + bv;
        size_t idx = (size_t)row*N + col;
        if (MODE==0) outB[idx] = f2b(v);
        else if (MODE==1) outF[idx] = v + resid[idx];
        else if (MODE==2){
          float g = 0.5f*v*(1.f + tanhf(0.7978845608028654f*(v + 0.044715f*v*v*v)));
          outB[idx] = f2b(g);
        }
        else if (MODE==3) outB[idx] = f2b(fmaxf(v, 0.f));
        else if (MODE==4) outF[idx] = v;
        else if (MODE==5) outF[idx] = v + pos[idx] + tok[col];
      }
    }
  }
}

// ---------------- LayerNorm: row of 1536, block per row ----------------
__global__ void ln_k(const float* __restrict__ in, const float* __restrict__ g,
                     const float* __restrict__ bta, float* __restrict__ xf,
                     u16* __restrict__ xb){
  const int row = blockIdx.x, t = threadIdx.x;
  const float* rp = in + (size_t)row*HM;
  float v[6]; float s=0.f, s2=0.f;
  #pragma unroll
  for (int i=0;i<6;i++){ v[i] = rp[t + i*256]; s += v[i]; s2 += v[i]*v[i]; }
  #pragma unroll
  for (int o=32;o;o>>=1){ s += __shfl_down(s,o,64); s2 += __shfl_down(s2,o,64); }
  __shared__ float red[8];
  if ((t&63)==0){ red[t>>6]=s; red[4+(t>>6)]=s2; }
  __syncthreads();
  s = red[0]+red[1]+red[2]+red[3]; s2 = red[4]+red[5]+red[6]+red[7];
  float mean = s*(1.f/1536.f);
  float var  = s2*(1.f/1536.f) - mean*mean;
  float inv  = rsqrtf(var + 1e-12f);
  #pragma unroll
  for (int i=0;i<6;i++){
    int c = t + i*256;
    float y = (v[i]-mean)*inv*g[c] + bta[c];
    xf[(size_t)row*HM + c] = y;
    xb[(size_t)row*HM + c] = f2b(y);
  }
}

// ---------------- fused block-sparse flash attention (split-K edges) ----------------
// grid = 496 mid blocks + 128 edge-split blocks; every block does 2 chunks (8 kblocks).
// mid:  b<496: h=b/62, qb=1+b%62 -> final ctx write.
// edge: e=b-496: split=e&7, idx=e>>3, h=idx>>1, qb=(idx&1)?63:0; kblocks split*8..+7;
//       writes unnormalized O + (m,l) partials, merged by attn_comb_k.
// sP is XOR-swizzled: byte ^= (row&7)<<4 (write and read agree; reads stay 16B-aligned).
__device__ inline int sp_off(int row, int colu16){
  return row*256 + ((((colu16)*2) ^ ((row&7)<<4)) >> 1);
}

__global__ __launch_bounds__(256, 2) void attn_k(
    const u16* __restrict__ qkv, const u16* __restrict__ vt,
    const int* __restrict__ kblocks, const int* __restrict__ amask,
    u16* __restrict__ ctx, float* __restrict__ pO,
    float* __restrict__ pm, float* __restrict__ pl){
  __shared__ __align__(16) u16 sQ[64][200];
  __shared__ __align__(16) u16 sP[64*256];
  __shared__ float swm[4][64];
  __shared__ float swl[4][64];
  __shared__ float s_m[64];
  __shared__ float s_l[64];
  __shared__ float s_al[64];

  const int t = threadIdx.x, w = t>>6, l = t&63;
  const int lr = l&15, lg = l>>4;
  const int b = blockIdx.x;
  int h, qb, split;
  bool partial;
  if (b < 496){ h = b/62; qb = 1 + b%62; split = 0; partial = false; }
  else { int e = b-496; split = e&7; int idx = e>>3; h = idx>>1; qb = (idx&1)?63:0; partial = true; }

  {
    const u16* qg = qkv + (size_t)(qb*64)*QKVN + h*192;
    #pragma unroll
    for (int i=0;i<6;i++){
      int idx = t + i*256;            // 0..1535
      int row = idx/24, c8 = idx%24;
      *reinterpret_cast<int4*>(&sQ[row][c8*8]) =
        *reinterpret_cast<const int4*>(qg + (size_t)row*QKVN + c8*8);
    }
  }
  if (t < 64){ s_m[t] = -3.0e38f; s_l[t] = 0.f; }
  __syncthreads();

  f32x4 accO[4][3] = {};
  const float scale = 0.07216878364870323f;   // 1/sqrt(192)

  for (int c = 0; c < 2; ++c){
    // ---- phase A: S = Q K^T for this wave's key-block (64 keys)
    const int jj = c*4 + w;
    const int kb = partial ? (split*8 + jj) : kblocks[(qb-1)*8 + jj];
    const u16* kp = qkv + (size_t)(kb*64)*QKVN + 1536 + h*192;
    f32x4 acc[4][4] = {};
    #pragma unroll
    for (int d0=0; d0<192; d0+=32){
      bf16x8 aq[4], bk_[4];
      #pragma unroll
      for (int i=0;i<4;i++)  aq[i]  = ld8(&sQ[i*16+lr][d0+lg*8]);
      #pragma unroll
      for (int jn=0;jn<4;jn++) bk_[jn] = ld8(kp + (size_t)(jn*16+lr)*QKVN + d0 + lg*8);
      #pragma unroll
      for (int i=0;i<4;i++)
        #pragma unroll
        for (int jn=0;jn<4;jn++)
          acc[i][jn] = __builtin_amdgcn_mfma_f32_16x16x32_bf16(aq[i], bk_[jn], acc[i][jn], 0,0,0);
    }
    float mcol[4];
    #pragma unroll
    for (int jn=0;jn<4;jn++)
      mcol[jn] = -1e9f*(1.f - (float)amask[kb*64 + jn*16 + lr]);
    float rmax[4][4];
    #pragma unroll
    for (int i=0;i<4;i++)
      #pragma unroll
      for (int r2=0;r2<4;r2++){
        float mx = -3.0e38f;
        #pragma unroll
        for (int jn=0;jn<4;jn++){
          float sv = acc[i][jn][r2]*scale + mcol[jn];
          acc[i][jn][r2] = sv;
          mx = fmaxf(mx, sv);
        }
        #pragma unroll
        for (int o=1;o<16;o<<=1) mx = fmaxf(mx, __shfl_xor(mx, o, 64));
        rmax[i][r2] = mx;
      }
    if (lr == 0){
      #pragma unroll
      for (int i=0;i<4;i++)
        #pragma unroll
        for (int r2=0;r2<4;r2++)
          swm[w][i*16+lg*4+r2] = rmax[i][r2];
    }
    __syncthreads();                       // B1: swm visible; prev PV done
    if (t < 64){
      float mo = s_m[t];
      float mn = fmaxf(fmaxf(fmaxf(swm[0][t], swm[1][t]), fmaxf(swm[2][t], swm[3][t])), mo);
      s_al[t] = __expf(mo - mn);
      s_m[t]  = mn;
    }
    __syncthreads();                       // B2: s_m / s_al visible
    // ---- phase C: P = exp(S-m) -> sP bf16 (swizzled); partial sums; rescale O
    #pragma unroll
    for (int i=0;i<4;i++)
      #pragma unroll
      for (int r2=0;r2<4;r2++){
        const int row = i*16 + lg*4 + r2;
        const float mrow = s_m[row];
        float ssum = 0.f;
        #pragma unroll
        for (int jn=0;jn<4;jn++){
          float p = __expf(acc[i][jn][r2] - mrow);
          ssum += p;
          sP[sp_off(row, w*64 + jn*16 + lr)] = f2b(p);
        }
        #pragma unroll
        for (int o=1;o<16;o<<=1) ssum += __shfl_xor(ssum, o, 64);
        if (lr == 0) swl[w][row] = ssum;
      }
    #pragma unroll
    for (int i=0;i<4;i++)
      #pragma unroll
      for (int r2=0;r2<4;r2++){
        float a = s_al[i*16+lg*4+r2];
        #pragma unroll
        for (int jn=0;jn<3;jn++) accO[i][jn][r2] *= a;
      }
    __syncthreads();                       // B3: sP / swl visible
    if (t < 64)
      s_l[t] = s_l[t]*s_al[t] + swl[0][t]+swl[1][t]+swl[2][t]+swl[3][t];
    // ---- phase E: O += P V (wave's 48 output dims, 256 chunk keys)
    int kb4[4];
    #pragma unroll
    for (int idx=0;idx<4;idx++)
      kb4[idx] = partial ? (split*8 + c*4 + idx) : kblocks[(qb-1)*8 + c*4 + idx];
    #pragma unroll
    for (int ks=0; ks<8; ks++){
      bf16x8 ap[4], bv_[3];
      #pragma unroll
      for (int i=0;i<4;i++) ap[i] = ld8(&sP[sp_off(i*16+lr, ks*32 + lg*8)]);
      const int sb = kb4[ks>>1]*64 + (ks&1)*32 + lg*8;
      #pragma unroll
      for (int jn=0;jn<3;jn++)
        bv_[jn] = ld8(vt + (size_t)(h*192 + w*48 + jn*16 + lr)*SEQ + sb);
      #pragma unroll
      for (int i=0;i<4;i++)
        #pragma unroll
        for (int jn=0;jn<3;jn++)
          accO[i][jn] = __builtin_amdgcn_mfma_f32_16x16x32_bf16(ap[i], bv_[jn], accO[i][jn], 0,0,0);
    }
  }
  __syncthreads();
  if (!partial){
    #pragma unroll
    for (int i=0;i<4;i++)
      #pragma unroll
      for (int r2=0;r2<4;r2++){
        const int row = i*16+lg*4+r2;
        const float inv = 1.f / s_l[row];
        #pragma unroll
        for (int jn=0;jn<3;jn++){
          const int col = h*192 + w*48 + jn*16 + lr;
          ctx[(size_t)(qb*64+row)*HM + col] = f2b(accO[i][jn][r2] * inv);
        }
      }
  } else {
    const int e = b - 496;
    #pragma unroll
    for (int i=0;i<4;i++)
      #pragma unroll
      for (int r2=0;r2<4;r2++){
        const int row = i*16+lg*4+r2;
        #pragma unroll
        for (int jn=0;jn<3;jn++){
          const int col = w*48 + jn*16 + lr;
          pO[((size_t)e*64 + row)*192 + col] = accO[i][jn][r2];
        }
      }
    if (t < 64){ pm[e*64 + t] = s_m[t]; pl[e*64 + t] = s_l[t]; }
  }
}

// merge 8 key-range splits for the 16 edge (h,qb) tiles
__global__ void attn_comb_k(const float* __restrict__ pO, const float* __restrict__ pm,
                            const float* __restrict__ pl, u16* __restrict__ ctx){
  const int b = blockIdx.x;            // 0..15
  const int h = b>>1, qb = (b&1)?63:0;
  const int t = threadIdx.x;
  __shared__ float sA[8][64];
  __shared__ float sInv[64];
  if (t < 64){
    float mv[8]; float M = -3.0e38f;
    #pragma unroll
    for (int s=0;s<8;s++){ mv[s] = pm[(b*8+s)*64 + t]; M = fmaxf(M, mv[s]); }
    float L = 0.f;
    #pragma unroll
    for (int s=0;s<8;s++){
      float a = __expf(mv[s]-M);
      sA[s][t] = a;
      L += pl[(b*8+s)*64 + t]*a;
    }
    sInv[t] = 1.f/L;
  }
  __syncthreads();
  #pragma unroll
  for (int i=0;i<48;i++){
    int idx = t + i*256;               // 0..12287
    int row = idx/192, col = idx%192;
    float acc = 0.f;
    #pragma unroll
    for (int s=0;s<8;s++)
      acc += sA[s][row] * pO[((size_t)(b*8+s)*64 + row)*192 + col];
    ctx[(size_t)(qb*64+row)*HM + h*192 + col] = f2b(acc * sInv[row]);
  }
}

// =====================================================================
extern "C" void kernel_launch(void* const* d_in, const int* in_sizes, int n_in,
                              void* d_out, int out_size, void* d_ws, size_t ws_size,
                              hipStream_t stream){
  const float* x       = (const float*)d_in[0];
  const float* proj_w  = (const float*)d_in[1];
  const float* proj_b  = (const float*)d_in[2];
  const float* pos_emb = (const float*)d_in[3];
  const float* tok_emb = (const float*)d_in[4];
  const float* embs    = (const float*)d_in[5];
  const float* embb    = (const float*)d_in[6];
  const float* Wq  = (const float*)d_in[7];
  const float* bq  = (const float*)d_in[8];
  const float* Wk  = (const float*)d_in[9];
  const float* bk  = (const float*)d_in[10];
  const float* Wv  = (const float*)d_in[11];
  const float* bv  = (const float*)d_in[12];
  const float* Wo  = (const float*)d_in[13];
  const float* bo  = (const float*)d_in[14];
  const float* l1s = (const float*)d_in[15];
  const float* l1b = (const float*)d_in[16];
  const float* Wi  = (const float*)d_in[17];
  const float* bi  = (const float*)d_in[18];
  const float* Wo2 = (const float*)d_in[19];
  const float* bo2 = (const float*)d_in[20];
  const float* l2s = (const float*)d_in[21];
  const float* l2b = (const float*)d_in[22];
  const float* cw1 = (const float*)d_in[23];
  const float* cb1 = (const float*)d_in[24];
  const float* cw2 = (const float*)d_in[25];
  const float* cb2 = (const float*)d_in[26];
  const int* amask = (const int*)d_in[27];
  const int* kblk  = (const int*)d_in[28];
  float* out = (float*)d_out;

  char* base = (char*)d_ws;
  size_t off = 0;
  auto carve = [&](size_t bytes)->char*{
    char* p = base + off; off += (bytes + 255) & ~(size_t)255; return p;
  };
  float* xf32  = (float*)carve(4096ULL*1536*4);
  float* preln = (float*)carve(4096ULL*1536*4);
  u16*   xbf   = (u16*)  carve(4096ULL*1536*2);
  u16*   xinbf = (u16*)  carve(4096ULL*1280*2);
  u16*   qkv   = (u16*)  carve(4096ULL*4608*2);
  u16*   vt    = (u16*)  carve(1536ULL*4096*2);
  u16*   ctx   = (u16*)  carve(4096ULL*1536*2);
  u16*   ff1   = (u16*)  carve(4096ULL*3072*2);
  u16*   cls1  = (u16*)  carve(4096ULL*512*2);
  u16*   wt    = (u16*)  carve(4608ULL*1536*2);
  float* b3    = (float*)carve(4608ULL*4);
  float* pO    = (float*)carve(128ULL*64*192*4);
  float* pm    = (float*)carve(128ULL*64*4);
  float* pl    = (float*)carve(128ULL*64*4);
  if (off > ws_size) return;   // workspace too small: fail cleanly

  const dim3 tb32(32,8);

  // ---- embedding ----
  cvt_k<<<5120, 256, 0, stream>>>(x, xinbf, 4096*1280/4);
  tconv<<<dim3(48,40), tb32, 0, stream>>>(proj_w, wt, 1280, 1536);
  gemm_k<5><<<dim3(12,32), 256, 0, stream>>>(xinbf, wt, proj_b, nullptr, pos_emb, tok_emb,
                                             nullptr, preln, 4096, 1536, 1280);
  ln_k<<<4096, 256, 0, stream>>>(preln, embs, embb, xf32, xbf);

  // ---- encoder layers ----
  for (int l = 0; l < 12; ++l){
    const float* wq  = Wq  + (size_t)l*1536*1536;
    const float* wk  = Wk  + (size_t)l*1536*1536;
    const float* wv  = Wv  + (size_t)l*1536*1536;
    const float* wo  = Wo  + (size_t)l*1536*1536;
    const float* wi  = Wi  + (size_t)l*1536*3072;
    const float* wo2 = Wo2 + (size_t)l*3072*1536;
    const float* bql = bq  + (size_t)l*1536;
    const float* bkl = bk  + (size_t)l*1536;
    const float* bvl = bv  + (size_t)l*1536;
    const float* bol = bo  + (size_t)l*1536;
    const float* bil = bi  + (size_t)l*3072;
    const float* bo2l= bo2 + (size_t)l*1536;
    const float* g1  = l1s + (size_t)l*1536;
    const float* be1 = l1b + (size_t)l*1536;
    const float* g2  = l2s + (size_t)l*1536;
    const float* be2 = l2b + (size_t)l*1536;

    // fused QKV
    tconv<<<dim3(48,48), tb32, 0, stream>>>(wq, wt,                  1536, 1536);
    tconv<<<dim3(48,48), tb32, 0, stream>>>(wk, wt + 1536ULL*1536,   1536, 1536);
    tconv<<<dim3(48,48), tb32, 0, stream>>>(wv, wt + 2ULL*1536*1536, 1536, 1536);
    concat3_k<<<6, 256, 0, stream>>>(b3, bql, bkl, bvl);
    gemm_k<0><<<dim3(36,32), 256, 0, stream>>>(xbf, wt, b3, nullptr, nullptr, nullptr,
                                               qkv, nullptr, 4096, 4608, 1536);
    vtrans_k<<<dim3(48,128), tb32, 0, stream>>>(qkv, vt);

    // fused block-sparse attention (uniform 2-chunk blocks + edge split-K)
    attn_k<<<624, 256, 0, stream>>>(qkv, vt, kblk, amask, ctx, pO, pm, pl);
    attn_comb_k<<<16, 256, 0, stream>>>(pO, pm, pl, ctx);

    // attention output projection + residual + LN
    tconv<<<dim3(48,48), tb32, 0, stream>>>(wo, wt, 1536, 1536);
    gemm_k<1><<<dim3(12,32), 256, 0, stream>>>(ctx, wt, bol, xf32, nullptr, nullptr,
                                               nullptr, preln, 4096, 1536, 1536);
    ln_k<<<4096, 256, 0, stream>>>(preln, g1, be1, xf32, xbf);

    // FFN
    tconv<<<dim3(96,48), tb32, 0, stream>>>(wi, wt, 1536, 3072);
    gemm_k<2><<<dim3(24,32), 256, 0, stream>>>(xbf, wt, bil, nullptr, nullptr, nullptr,
                                               ff1, nullptr, 4096, 3072, 1536);
    tconv<<<dim3(48,96), tb32, 0, stream>>>(wo2, wt, 3072, 1536);
    gemm_k<1><<<dim3(12,32), 256, 0, stream>>>(ff1, wt, bo2l, xf32, nullptr, nullptr,
                                               nullptr, preln, 4096, 1536, 3072);
    ln_k<<<4096, 256, 0, stream>>>(preln, g2, be2, xf32, xbf);
  }

  // ---- classifier head ----
  tconv<<<dim3(16,48), tb32, 0, stream>>>(cw1, wt, 1536, 512);
  gemm_k<3><<<dim3(4,32), 256, 0, stream>>>(xbf, wt, cb1, nullptr, nullptr, nullptr,
                                            cls1, nullptr, 4096, 512, 1536);
  tconv<<<dim3(8,16), tb32, 0, stream>>>(cw2, wt, 512, 256);
  gemm_k<4><<<dim3(2,32), 256, 0, stream>>>(cls1, wt, cb2, nullptr, nullptr, nullptr,
                                            nullptr, out, 4096, 256, 512);

  (void)in_sizes; (void)n_in; (void)out_size;
}